// Round 6
// baseline (142.538 us; speedup 1.0000x reference)
//
#include <hip/hip_runtime.h>
#include <stdint.h>

#define IN_F  4096
#define OUT_F 4096
#define BW    512
#define WB2   1280   // padded k-window per 256-col tile: [bcol-512, bcol+768)
#define BM    256
#define BN    256

typedef __bf16 bf16x8 __attribute__((ext_vector_type(8)));
typedef float  f32x4  __attribute__((ext_vector_type(4)));

__device__ __forceinline__ int band_start(int o) {
    if (o <= 512)  return o * 513 + ((o * (o - 1)) >> 1);
    if (o <= 3584) return 393472 + (o - 512) * 1025;
    const int d = o - 3584;
    return 3542272 + (((1024 + 4609 - o) * d) >> 1);
}

__device__ __forceinline__ uint16_t f32_to_bf16(float f) {
    uint32_t u = __builtin_bit_cast(uint32_t, f);
    u += 0x7FFFu + ((u >> 16) & 1u);   // RNE
    return (uint16_t)(u >> 16);
}

// ---- pass 1: x fp32 -> bf16 dense [M][4096]
__global__ __launch_bounds__(256) void cvt_x(const float* __restrict__ x,
                                             uint16_t* __restrict__ xb, int n4) {
    const int stride = gridDim.x * 256;
    for (int i = blockIdx.x * 256 + threadIdx.x; i < n4; i += stride) {
        const float4 v = reinterpret_cast<const float4*>(x)[i];
        const uint32_t lo = (uint32_t)f32_to_bf16(v.x) | ((uint32_t)f32_to_bf16(v.y) << 16);
        const uint32_t hi = (uint32_t)f32_to_bf16(v.z) | ((uint32_t)f32_to_bf16(v.w) << 16);
        reinterpret_cast<uint2*>(xb)[i] = make_uint2(lo, hi);
    }
}

// ---- pass 2: densify band -> wd[o][j], j indexes k = (o&~255)-512+j, zero outside band
__global__ __launch_bounds__(256) void cvt_w(const float* __restrict__ wv,
                                             uint16_t* __restrict__ wd) {
    const int o = blockIdx.y;
    const int j = blockIdx.x * 256 + threadIdx.x;     // 0..1279
    const int i = (o & ~(BM - 1)) - BW + j;
    uint16_t v = 0;
    if (i >= o - BW && i <= o + BW && i >= 0 && i < IN_F) {
        const int lo = (o > BW) ? (o - BW) : 0;
        v = f32_to_bf16(wv[band_start(o) + (i - lo)]);
    }
    wd[o * WB2 + j] = v;
}

// ---- pass 3: 256x256, BK=64, 8-phase counted-vmcnt schedule (m201 template port)
// LDS: bufE (even K64 tile): A@0 (h0 0,h1 16384), B@32768 (h0,h1 49152)
//      bufO (odd):           A@65536, 81920       B@98304, 114688
__global__ __launch_bounds__(512, 2) void band_gemm_v6(
    const uint16_t* __restrict__ xb,
    const uint16_t* __restrict__ wd,
    const float* __restrict__ bias,
    float* __restrict__ out)
{
    __shared__ __align__(128) uint8_t lds[131072];

    // bx-grouped XCD mapping: XCD x owns column panels {2x, 2x+1}; B stays L2-hot
    const int id  = blockIdx.x;
    const int xcd = id & 7;
    const int r   = id >> 3;
    const int bx  = 2 * xcd + (r & 1);
    const int by  = r >> 1;
    const int brow = by * BM;
    const int bcol = bx * BN;

    const int wlo    = bcol - BW;
    const int kstart = wlo > 0 ? wlo : 0;
    const int kend   = (bcol + BN + BW) < IN_F ? (bcol + BN + BW) : IN_F;
    const int nt     = (kend - kstart) >> 6;      // 12/16/20 K64 tiles (always even)
    const int niter  = nt >> 1;
    const int j0     = kstart - wlo;

    const int tid  = threadIdx.x;
    const int w    = tid >> 6;
    const int lane = tid & 63;
    const int ln   = lane & 15;
    const int kc   = lane >> 4;
    const int wm   = w >> 2;            // M half (128 rows)
    const int wn   = w & 3;             // N quarter (64 cols)

    // staging: unit = 64 rows x 128 B; LDS(row,c) holds global chunk c ^ (row&7)
    const int srow = tid >> 3;
    const int csrc = (tid & 7) ^ (srow & 7);
    const uint16_t* aSrc = xb + (size_t)(brow + srow) * IN_F + kstart + csrc * 8;
    const uint16_t* bSrc = wd + (size_t)(bcol + srow) * WB2 + j0 + csrc * 8;

#define GLOAD(srcp, dst_off)                                                             \
    __builtin_amdgcn_global_load_lds(                                                    \
        (const __attribute__((address_space(1))) uint32_t*)(srcp),                       \
        (__attribute__((address_space(3))) uint32_t*)(lds + (dst_off) + (w << 10)),      \
        16, 0, 0)

    // stage half-tile (128 rows x 64 k) of tile v, half h -> 2 gloads
#define STG_A(v, h, dst) { const uint16_t* p_ = aSrc + (size_t)((h) * 128) * IN_F + (v) * 64; \
        GLOAD(p_, dst); GLOAD(p_ + (size_t)64 * IN_F, (dst) + 8192); }
#define STG_B(v, h, dst) { const uint16_t* p_ = bSrc + (size_t)((h) * 128) * WB2 + (v) * 64;  \
        GLOAD(p_, dst); GLOAD(p_ + (size_t)64 * WB2, (dst) + 8192); }

    // fragment addressing (proven zero-conflict swizzle); k-step 1 = ^64
    const int cswz     = (kc ^ (ln & 7)) << 4;
    const int aRowBase = wm * 16384 + (ln << 7);
    const int bRowBase = (wn >> 1) * 16384 + (((wn & 1) * 64 + ln) << 7);

#define LD_AF(BB, MQ) {                                                                  \
    _Pragma("unroll")                                                                    \
    for (int a_ = 0; a_ < 4; ++a_) {                                                     \
        af[a_][0] = *(const bf16x8*)(lds + (BB) + aRowBase + (MQ) * 8192 + a_ * 2048 + cswz);        \
        af[a_][1] = *(const bf16x8*)(lds + (BB) + aRowBase + (MQ) * 8192 + a_ * 2048 + (cswz ^ 64)); \
    } }
#define LD_BF(BB, NQ, BF) {                                                              \
    _Pragma("unroll")                                                                    \
    for (int n_ = 0; n_ < 2; ++n_) {                                                     \
        BF[n_][0] = *(const bf16x8*)(lds + (BB) + bRowBase + (NQ) * 4096 + n_ * 2048 + cswz);        \
        BF[n_][1] = *(const bf16x8*)(lds + (BB) + bRowBase + (NQ) * 4096 + n_ * 2048 + (cswz ^ 64)); \
    } }
#define MFMA16(MQ, NQ, BF) {                                                             \
    _Pragma("unroll")                                                                    \
    for (int a_ = 0; a_ < 4; ++a_) {                                                     \
        _Pragma("unroll")                                                                \
        for (int n_ = 0; n_ < 2; ++n_) {                                                 \
            acc[(MQ)*4+a_][(NQ)*2+n_] = __builtin_amdgcn_mfma_f32_16x16x32_bf16(         \
                af[a_][0], BF[n_][0], acc[(MQ)*4+a_][(NQ)*2+n_], 0, 0, 0);               \
            acc[(MQ)*4+a_][(NQ)*2+n_] = __builtin_amdgcn_mfma_f32_16x16x32_bf16(         \
                af[a_][1], BF[n_][1], acc[(MQ)*4+a_][(NQ)*2+n_], 0, 0, 0);               \
        } } }
#define PH_SYNC  __builtin_amdgcn_s_barrier();                                           \
                 asm volatile("s_waitcnt lgkmcnt(0)" ::: "memory");                      \
                 __builtin_amdgcn_sched_barrier(0);                                      \
                 __builtin_amdgcn_s_setprio(1)
#define PH_END   __builtin_amdgcn_s_setprio(0);                                          \
                 __builtin_amdgcn_s_barrier()

    f32x4 acc[8][4] = {};

    // prologue: tile 0 complete + {B(1)h0, A(1)h0}; retire tile 0, keep 4 in flight
    STG_A(0, 0, 0);      STG_A(0, 1, 16384);
    STG_B(0, 0, 32768);  STG_B(0, 1, 49152);
    STG_B(1, 0, 98304);  STG_A(1, 0, 65536);
    asm volatile("s_waitcnt vmcnt(4)" ::: "memory");
    __builtin_amdgcn_s_barrier();

    for (int t = 0; t < niter; ++t) {
        const int u   = 2 * t;
        const bool st = (t + 1 < niter);
        bf16x8 af[4][2], bf0[2][2], bf1[2][2];

        // P1: tile u quadrant (0,0); stage A(u+1)h1
        LD_AF(0, 0); LD_BF(32768, 0, bf0);
        STG_A(u + 1, 1, 81920);
        PH_SYNC; MFMA16(0, 0, bf0); PH_END;
        // P2: (0,1); stage B(u+1)h1
        LD_BF(32768, 1, bf1);
        STG_B(u + 1, 1, 114688);
        PH_SYNC; MFMA16(0, 1, bf1); PH_END;
        // P3: (1,1); stage B(u+2)h0
        LD_AF(0, 1);
        if (st) STG_B(u + 2, 0, 32768);
        PH_SYNC; MFMA16(1, 1, bf1); PH_END;
        // P4: (1,0); stage A(u+2)h0; counted wait -> tile u+1 resident
        if (st) STG_A(u + 2, 0, 0);
        __builtin_amdgcn_s_barrier();
        __builtin_amdgcn_s_setprio(1);
        MFMA16(1, 0, bf0);
        __builtin_amdgcn_s_setprio(0);
        if (st) { asm volatile("s_waitcnt vmcnt(4)" ::: "memory"); }
        else    { asm volatile("s_waitcnt vmcnt(0)" ::: "memory"); }
        __builtin_amdgcn_s_barrier();
        // P5: tile u+1 quadrant (0,0); stage A(u+2)h1
        LD_AF(65536, 0); LD_BF(98304, 0, bf0);
        if (st) STG_A(u + 2, 1, 16384);
        PH_SYNC; MFMA16(0, 0, bf0); PH_END;
        // P6: (0,1); stage B(u+2)h1
        LD_BF(98304, 1, bf1);
        if (st) STG_B(u + 2, 1, 49152);
        PH_SYNC; MFMA16(0, 1, bf1); PH_END;
        // P7: (1,1); stage B(u+3)h0
        LD_AF(65536, 1);
        if (st) STG_B(u + 3, 0, 98304);
        PH_SYNC; MFMA16(1, 1, bf1); PH_END;
        // P8: (1,0); stage A(u+3)h0; counted wait -> tile u+2 resident
        if (st) STG_A(u + 3, 0, 65536);
        __builtin_amdgcn_s_barrier();
        __builtin_amdgcn_s_setprio(1);
        MFMA16(1, 0, bf0);
        __builtin_amdgcn_s_setprio(0);
        if (st) { asm volatile("s_waitcnt vmcnt(4)" ::: "memory"); }
        else    { asm volatile("s_waitcnt vmcnt(0)" ::: "memory"); }
        __builtin_amdgcn_s_barrier();
    }
#undef STG_A
#undef STG_B
#undef GLOAD

    // epilogue: C/D map col = lane&15, row = (lane>>4)*4 + q  (verified R2-R5)
    const int ocol = bcol + wn * 64 + ln;
    float bsv[4];
    #pragma unroll
    for (int n = 0; n < 4; ++n) bsv[n] = bias[ocol + n * 16];

    #pragma unroll
    for (int a = 0; a < 8; ++a) {
        #pragma unroll
        for (int q = 0; q < 4; ++q) {
            const int row = brow + wm * 128 + a * 16 + (kc << 2) + q;
            float* po = out + (size_t)row * OUT_F + ocol;
            #pragma unroll
            for (int n = 0; n < 4; ++n)
                po[n * 16] = acc[a][n][q] + bsv[n];
        }
    }
}

// ---- fallback (ws too small / odd M): fp32 tiled kernel, known correct
__global__ __launch_bounds__(256) void band_gemm_f32(
    const float* __restrict__ x, const float* __restrict__ wv,
    const float* __restrict__ bias, float* __restrict__ out, int M)
{
    __shared__ float Xs[128][33];
    __shared__ float Ws[32][130];
    const int tid = threadIdx.x;
    const int tx = tid & 15, ty = tid >> 4;
    const int bcol = blockIdx.x * 128, brow = blockIdx.y * 128;
    const int klo = (bcol >= BW) ? (bcol - BW) : 0;
    const int khi = min(IN_F, bcol + 128 + BW);
    float acc[8][8];
    #pragma unroll
    for (int a = 0; a < 8; ++a)
        #pragma unroll
        for (int b = 0; b < 8; ++b) acc[a][b] = 0.f;
    const int xc4 = (tid & 7) * 4, xr0 = tid >> 3;
    const int wc = tid & 31, wr0 = tid >> 5;
    for (int k0 = klo; k0 < khi; k0 += 32) {
        #pragma unroll
        for (int p = 0; p < 4; ++p) {
            const int rr = xr0 + 32 * p;
            const float4 v = *reinterpret_cast<const float4*>(&x[(size_t)(brow + rr) * IN_F + (k0 + xc4)]);
            Xs[rr][xc4 + 0] = v.x; Xs[rr][xc4 + 1] = v.y; Xs[rr][xc4 + 2] = v.z; Xs[rr][xc4 + 3] = v.w;
        }
        const int i = k0 + wc;
        #pragma unroll
        for (int p = 0; p < 16; ++p) {
            const int rr = wr0 + 8 * p;
            const int o = bcol + rr;
            const int lo = (o >= BW) ? (o - BW) : 0;
            float v = 0.f;
            if (i >= o - BW && i <= o + BW) v = wv[band_start(o) + (i - lo)];
            Ws[wc][rr] = v;
        }
        __syncthreads();
        #pragma unroll
        for (int k = 0; k < 32; ++k) {
            float am[8];
            #pragma unroll
            for (int a = 0; a < 8; ++a) am[a] = Xs[ty * 8 + a][k];
            float bo[8];
            #pragma unroll
            for (int b = 0; b < 4; ++b) { bo[b] = Ws[k][tx * 4 + b]; bo[4 + b] = Ws[k][tx * 4 + 64 + b]; }
            #pragma unroll
            for (int a = 0; a < 8; ++a)
                #pragma unroll
                for (int b = 0; b < 8; ++b) acc[a][b] = fmaf(am[a], bo[b], acc[a][b]);
        }
        __syncthreads();
    }
    #pragma unroll
    for (int a = 0; a < 8; ++a) {
        const size_t row = (size_t)(brow + ty * 8 + a);
        #pragma unroll
        for (int b = 0; b < 4; ++b) {
            out[row * OUT_F + bcol + tx * 4 + b]      = acc[a][b]     + bias[bcol + tx * 4 + b];
            out[row * OUT_F + bcol + tx * 4 + 64 + b] = acc[a][4 + b] + bias[bcol + tx * 4 + 64 + b];
        }
    }
}

extern "C" void kernel_launch(void* const* d_in, const int* in_sizes, int n_in,
                              void* d_out, int out_size, void* d_ws, size_t ws_size,
                              hipStream_t stream) {
    const float* x    = (const float*)d_in[0];
    const float* wv   = (const float*)d_in[1];
    const float* bias = (const float*)d_in[2];
    float* out        = (float*)d_out;

    const int M = in_sizes[0] / IN_F;                         // 8192
    const size_t xb_bytes = (size_t)M * IN_F * 2;             // 64 MB
    const size_t wd_bytes = (size_t)OUT_F * WB2 * 2;          // 10.5 MB

    if (ws_size >= xb_bytes + wd_bytes && (M % BM) == 0) {
        uint16_t* xb  = (uint16_t*)d_ws;
        uint16_t* wdp = (uint16_t*)((uint8_t*)d_ws + xb_bytes);
        cvt_x<<<2048, 256, 0, stream>>>(x, xb, M * IN_F / 4);
        cvt_w<<<dim3(WB2 / 256, OUT_F), 256, 0, stream>>>(wv, wdp);
        band_gemm_v6<<<(M / BM) * (OUT_F / BN), 512, 0, stream>>>(xb, wdp, bias, out);
    } else {
        dim3 grid(OUT_F / 128, M / 128);
        band_gemm_f32<<<grid, 256, 0, stream>>>(x, wv, bias, out, M);
    }
}